// Round 14
// baseline (98.477 us; speedup 1.0000x reference)
//
#include <hip/hip_runtime.h>

#define NN 4096   // H*W
#define CC 256    // channels
#define DQ 32     // d_qk
#define NB 4      // batch

typedef float        f32x4  __attribute__((ext_vector_type(4)));
typedef float        f32x16 __attribute__((ext_vector_type(16)));
typedef short        s16x4  __attribute__((ext_vector_type(4)));
typedef short        s16x8  __attribute__((ext_vector_type(8)));
typedef unsigned int u32x2  __attribute__((ext_vector_type(2)));
typedef unsigned int u32x4  __attribute__((ext_vector_type(4)));

// float -> bf16 bits, round-to-nearest-even
__device__ __forceinline__ unsigned short f2bf(float f) {
  unsigned u = __builtin_bit_cast(unsigned, f);
  u += 0x7fffu + ((u >> 16) & 1u);
  return (unsigned short)(u >> 16);
}

__device__ __forceinline__ f32x4 mfma16(s16x4 a, s16x4 b, f32x4 c) {
  return __builtin_amdgcn_mfma_f32_16x16x16bf16_1k(a, b, c, 0, 0, 0);
}
__device__ __forceinline__ f32x16 mfma32b(s16x8 a, s16x8 b, f32x16 c) {
  return __builtin_amdgcn_mfma_f32_32x32x16_bf16(a, b, c, 0, 0, 0);
}

__device__ __forceinline__ s16x4 lo4(u32x4 r) { u32x2 t = {r[0], r[1]}; return __builtin_bit_cast(s16x4, t); }
__device__ __forceinline__ s16x4 hi4(u32x4 r) { u32x2 t = {r[2], r[3]}; return __builtin_bit_cast(s16x4, t); }
__device__ __forceinline__ s16x8 bc8(u32x4 r) { return __builtin_bit_cast(s16x8, r); }

// raw v_exp_f32: scores are bounded (|s|<~8), no denormal fixups needed.
__device__ __forceinline__ float fexp2(float x) {
  float r;
  asm("v_exp_f32 %0, %1" : "=v"(r) : "v"(x));
  return r;
}

#define XLS 264   // proj LDS row stride (256 + 8 pad)

// ---------------- Kernel A: fused QKV projection (R7-verified layouts; 32-col tiles) ----------------
// QT: [B][N][32] bf16 row-contiguous.
// KT: LANE-ORDERED [B][jt=128][kh=2][lane=64][8] bf16.
// Vm: LANE-ORDERED [B][jt=128][cq=8][kh=2][lane=64][8] bf16 (k-slot bijection).
// 32-column n-tiles -> grid 128xNB -> 2 blocks/CU (R13's proj was 1-block/CU latency-bound).
__global__ __launch_bounds__(256)
void proj_kernel(const float* __restrict__ x,
                 const float* __restrict__ Wq, const float* __restrict__ bq,
                 const float* __restrict__ Wk, const float* __restrict__ bk,
                 const float* __restrict__ Wv, const float* __restrict__ bv,
                 unsigned short* __restrict__ QT,
                 unsigned short* __restrict__ KT,
                 unsigned short* __restrict__ Vm) {
  __shared__ unsigned short Xl[32 * XLS];
  const int tid = threadIdx.x;
  const int b   = blockIdx.y;
  const int n0  = blockIdx.x * 32;

  {
    const int n4 = (tid & 7) * 4;
    int c = tid >> 3;                  // 0..31, 8 passes of 32 c
    const float* xp = x + (size_t)(b * CC + c) * NN + n0 + n4;
    #pragma unroll
    for (int it = 0; it < 8; ++it) {
      f32x4 v = *reinterpret_cast<const f32x4*>(xp);
      #pragma unroll
      for (int e = 0; e < 4; ++e)
        Xl[(n4 + e) * XLS + c] = f2bf(v[e]);
      c += 32; xp += (size_t)32 * NN;
    }
  }
  __syncthreads();

  const int wave = tid >> 6;
  const int lane = tid & 63;
  const int l16  = lane & 15;
  const int g    = lane >> 4;
  const float qscale = 0.0901684400555602f;  // log2(e)/16

  const float* wrowp[5];
  float wsc[5];
  #pragma unroll
  for (int rt = 0; rt < 5; ++rt) {
    const int R0 = (wave * 5 + rt) * 16;
    const int R  = R0 + l16;
    if (R0 < 32)      { wrowp[rt] = Wq + R * CC;        wsc[rt] = qscale; }
    else if (R0 < 64) { wrowp[rt] = Wk + (R - 32) * CC; wsc[rt] = 1.0f; }
    else              { wrowp[rt] = Wv + (R - 64) * CC; wsc[rt] = 1.0f; }
  }

  f32x4 acc[5][2];
  #pragma unroll
  for (int rt = 0; rt < 5; ++rt)
    #pragma unroll
    for (int nt = 0; nt < 2; ++nt) acc[rt][nt] = (f32x4){0.f, 0.f, 0.f, 0.f};

  for (int k0 = 0; k0 < CC; k0 += 32) {
    s16x4 xb[2][2];
    #pragma unroll
    for (int nt = 0; nt < 2; ++nt) {
      const unsigned short* p = &Xl[(l16 + 16 * nt) * XLS + k0 + 8 * g];
      u32x4 raw = *reinterpret_cast<const u32x4*>(p);
      xb[nt][0] = lo4(raw);
      xb[nt][1] = hi4(raw);
    }
    #pragma unroll
    for (int rt = 0; rt < 5; ++rt) {
      const float* wp = wrowp[rt] + k0 + 8 * g;
      f32x4 w0 = *reinterpret_cast<const f32x4*>(wp);
      f32x4 w1 = *reinterpret_cast<const f32x4*>(wp + 4);
      const float sc = wsc[rt];
      s16x4 wa0, wa1;
      #pragma unroll
      for (int e = 0; e < 4; ++e) {
        wa0[e] = (short)f2bf(w0[e] * sc);
        wa1[e] = (short)f2bf(w1[e] * sc);
      }
      #pragma unroll
      for (int nt = 0; nt < 2; ++nt) {
        acc[rt][nt] = mfma16(wa0, xb[nt][0], acc[rt][nt]);
        acc[rt][nt] = mfma16(wa1, xb[nt][1], acc[rt][nt]);
      }
    }
  }

  #pragma unroll
  for (int rt = 0; rt < 5; ++rt) {
    const int R0 = (wave * 5 + rt) * 16;
    float bias_r[4];
    {
      const float* bp; float bsc;
      if (R0 < 32)      { bp = bq + R0;      bsc = qscale; }
      else if (R0 < 64) { bp = bk + R0 - 32; bsc = 1.0f; }
      else              { bp = bv + R0 - 64; bsc = 1.0f; }
      #pragma unroll
      for (int r = 0; r < 4; ++r) bias_r[r] = bp[4 * g + r] * bsc;
    }
    #pragma unroll
    for (int nt = 0; nt < 2; ++nt) {
      const int n = n0 + nt * 16 + l16;
      float v0 = acc[rt][nt][0] + bias_r[0];
      float v1 = acc[rt][nt][1] + bias_r[1];
      float v2 = acc[rt][nt][2] + bias_r[2];
      float v3 = acc[rt][nt][3] + bias_r[3];
      if (R0 < 32) {
        u32x2 pk = { (unsigned)f2bf(v0) | ((unsigned)f2bf(v1) << 16),
                     (unsigned)f2bf(v2) | ((unsigned)f2bf(v3) << 16) };
        unsigned short* dst = QT + ((size_t)b * NN + n) * DQ + R0 + 4 * g;
        *reinterpret_cast<u32x2*>(dst) = pk;
      } else if (R0 < 64) {
        const int d0     = R0 - 32 + 4 * g;
        const int kh     = d0 >> 4;
        const int g2v    = (d0 >> 3) & 1;
        const int e0     = d0 & 7;
        const int jt     = n >> 5;
        const int lane_t = (n & 31) + 32 * g2v;
        u32x2 pk = { (unsigned)f2bf(v0) | ((unsigned)f2bf(v1) << 16),
                     (unsigned)f2bf(v2) | ((unsigned)f2bf(v3) << 16) };
        unsigned short* kd = KT + (((size_t)(b * 128 + jt) * 2 + kh) * 64 + lane_t) * 8 + e0;
        *reinterpret_cast<u32x2*>(kd) = pk;
      } else {
        const int c0  = R0 - 64 + 4 * g;
        const int cq  = c0 >> 5;
        const int cl  = c0 & 31;
        const int jt  = n0 >> 5;
        const int kh  = nt & 1;
        const int g2v = (l16 >> 2) & 1;
        const int e   = (l16 & 3) | (((l16 >> 3) & 1) << 2);
        unsigned short* vd = Vm
          + ((((size_t)(b * 128 + jt) * 8 + cq) * 2 + kh) * 64 + (cl + 32 * g2v)) * 8 + e;
        vd[0]  = f2bf(v0);
        vd[8]  = f2bf(v1);
        vd[16] = f2bf(v2);
        vd[24] = f2bf(v3);
      }
    }
  }
}

// ---------------- Kernel B: flash attention, lag-1 pipelined, 2x-redundant softmax ----------------
// 256 threads, 4 waves = strip(2) x chv(2), 1 wave/SIMD (512-reg budget, R13-proven).
// Wave: 32 q x 128 c x ALL 128 j-tiles. Per iter: QK(t) 2 MFMA -> PV(t-1) 8 MFMA
// + 2 l-MFMA (using prev P) -> loads(t+1) -> softmax(t) on VALU (overlaps MFMA pipe).
// l via ones-MFMA, NO shfl fold (32x32 MFMA sums all 16 k incl. both g2 halves;
// R10-12's fold was a double-count).

#define SM16(SS, P0_, P1_) { \
  const float p0=fexp2(SS[0]),  p1=fexp2(SS[1]),  p2=fexp2(SS[2]),  p3=fexp2(SS[3]); \
  const float p4=fexp2(SS[4]),  p5=fexp2(SS[5]),  p6=fexp2(SS[6]),  p7=fexp2(SS[7]); \
  const float p8=fexp2(SS[8]),  p9=fexp2(SS[9]),  pa=fexp2(SS[10]), pb=fexp2(SS[11]); \
  const float pc=fexp2(SS[12]), pd=fexp2(SS[13]), pe=fexp2(SS[14]), pf=fexp2(SS[15]); \
  unsigned q0,q1,q2,q3,q4,q5,q6,q7; \
  asm("v_cvt_pk_bf16_f32 %0, %1, %2" : "=v"(q0) : "v"(p0), "v"(p1)); \
  asm("v_cvt_pk_bf16_f32 %0, %1, %2" : "=v"(q1) : "v"(p2), "v"(p3)); \
  asm("v_cvt_pk_bf16_f32 %0, %1, %2" : "=v"(q2) : "v"(p4), "v"(p5)); \
  asm("v_cvt_pk_bf16_f32 %0, %1, %2" : "=v"(q3) : "v"(p6), "v"(p7)); \
  asm("v_cvt_pk_bf16_f32 %0, %1, %2" : "=v"(q4) : "v"(p8), "v"(p9)); \
  asm("v_cvt_pk_bf16_f32 %0, %1, %2" : "=v"(q5) : "v"(pa), "v"(pb)); \
  asm("v_cvt_pk_bf16_f32 %0, %1, %2" : "=v"(q6) : "v"(pc), "v"(pd)); \
  asm("v_cvt_pk_bf16_f32 %0, %1, %2" : "=v"(q7) : "v"(pe), "v"(pf)); \
  u32x4 _w0 = {q0,q1,q2,q3}, _w1 = {q4,q5,q6,q7}; \
  P0_ = bc8(_w0); P1_ = bc8(_w1); }

// PV + l cluster on prev P (8 + 2 MFMA)
#define PVONLY_IMPL(V0, V1, V2, V3, V4, V5, V6, V7) { \
  o0 = mfma32b(bc8(V0), P0, o0); \
  o0 = mfma32b(bc8(V1), P1, o0); \
  o1 = mfma32b(bc8(V2), P0, o1); \
  o1 = mfma32b(bc8(V3), P1, o1); \
  o2 = mfma32b(bc8(V4), P0, o2); \
  o2 = mfma32b(bc8(V5), P1, o2); \
  o3 = mfma32b(bc8(V6), P0, o3); \
  o3 = mfma32b(bc8(V7), P1, o3); \
  lacc = mfma32b(ones8, P0, lacc); \
  lacc = mfma32b(ones8, P1, lacc); }
#define PVONLY(VS) PVONLY_IMPL(VS)

#define LOADK_IMPL(T, KA, KB) { \
  const size_t _o = (size_t)(T) * 1024; \
  KA = *(const u32x4*)(Kb + _o); \
  KB = *(const u32x4*)(Kb + _o + 512); }
#define LOADK(T, KS) LOADK_IMPL(T, KS)

#define LOADV_IMPL(T, V0, V1, V2, V3, V4, V5, V6, V7) { \
  const size_t _o = (size_t)(T) * 8192; \
  V0 = *(const u32x4*)(Vb + _o); \
  V1 = *(const u32x4*)(Vb + _o + 512); \
  V2 = *(const u32x4*)(Vb + _o + 1024); \
  V3 = *(const u32x4*)(Vb + _o + 1536); \
  V4 = *(const u32x4*)(Vb + _o + 2048); \
  V5 = *(const u32x4*)(Vb + _o + 2560); \
  V6 = *(const u32x4*)(Vb + _o + 3072); \
  V7 = *(const u32x4*)(Vb + _o + 3584); }
#define LOADV(T, VS) LOADV_IMPL(T, VS)

// iter t: QK(t) [KA,KB] -> PV(t-1)+l [prev P, PV set] -> loads(t+1) -> SM16 -> P
#define ITER_IMPL(T, KA, KB, PV0, PV1, PV2, PV3, PV4, PV5, PV6, PV7, \
                     NKA, NKB, NV0, NV1, NV2, NV3, NV4, NV5, NV6, NV7) { \
  f32x16 ss = mfma32b(bc8(KA), qf0, zz16); \
  ss = mfma32b(bc8(KB), qf1, ss); \
  PVONLY_IMPL(PV0, PV1, PV2, PV3, PV4, PV5, PV6, PV7); \
  LOADK_IMPL((T) + 1, NKA, NKB); \
  LOADV_IMPL((T) + 1, NV0, NV1, NV2, NV3, NV4, NV5, NV6, NV7); \
  SM16(ss, P0, P1); }
#define ITER(T, KC, PVS, KN, VNS) ITER_IMPL(T, KC, PVS, KN, VNS)

#define KSET0 k0a, k0b
#define KSET1 k1a, k1b
#define VSET0 vx0, vx1, vx2, vx3, vx4, vx5, vx6, vx7
#define VSET1 vy0, vy1, vy2, vy3, vy4, vy5, vy6, vy7

#define STORE_CT(CT, OV) { \
  _Pragma("unroll") \
  for (int r = 0; r < 16; ++r) { \
    const int c = chv * 128 + (CT) * 32 + (r & 3) + 8 * (r >> 2) + 4 * g2; \
    const size_t adr = ((size_t)b * CC + c) * NN + i; \
    out[adr] = ga * OV[r] + x[adr]; } }

__global__ __launch_bounds__(256, 1)
void attn_kernel(const unsigned short* __restrict__ QT,
                 const unsigned short* __restrict__ KT,
                 const unsigned short* __restrict__ Vm,
                 const float* __restrict__ x,
                 const float* __restrict__ gamma,
                 float* __restrict__ out) {
  const int tid  = threadIdx.x;
  const int wave = tid >> 6;
  const int s    = wave >> 1;    // strip (32 q)
  const int chv  = wave & 1;     // channel half (128 c)
  const int lane = tid & 63;
  const int l31  = lane & 31;
  const int g2   = lane >> 5;

  // XCD swizzle: gid%8 -> XCD; one batch per XCD pair
  const int gid = blockIdx.x;
  const int rr  = gid & 7;
  const int qq  = gid >> 3;
  const int b   = rr >> 1;
  const int xt  = (qq << 1) | (rr & 1);
  const int ibase = xt * 64;
  const float gamma0 = gamma[0];

  // Q frags for this wave's strip
  const unsigned short* Qb = QT + ((size_t)b * NN + ibase + s * 32 + l31) * DQ;
  const s16x8 qf0 = bc8(*(const u32x4*)(Qb + 8 * g2));
  const s16x8 qf1 = bc8(*(const u32x4*)(Qb + 16 + 8 * g2));

  const unsigned _one2 = 0x3F803F80u;  // 2x bf16 1.0
  u32x4 _ones = {_one2, _one2, _one2, _one2};
  const s16x8 ones8 = bc8(_ones);

  f32x16 o0, o1, o2, o3, lacc, zz16;
  #pragma unroll
  for (int r = 0; r < 16; ++r) {
    o0[r] = 0.f; o1[r] = 0.f; o2[r] = 0.f; o3[r] = 0.f; lacc[r] = 0.f; zz16[r] = 0.f;
  }

  const unsigned short* Kb = KT + (size_t)b * 128 * 1024 + lane * 8;
  const unsigned short* Vb = Vm + ((size_t)b * 128 * 8 + chv * 4) * 1024 + lane * 8;

  u32x4 k0a, k0b, k1a, k1b;
  u32x4 vx0, vx1, vx2, vx3, vx4, vx5, vx6, vx7;
  u32x4 vy0, vy1, vy2, vy3, vy4, vy5, vy6, vy7;
  s16x8 P0, P1;

  // prologue: tiles 0,1; softmax(0)
  LOADK(0, KSET0);
  LOADV(0, VSET0);
  LOADK(1, KSET1);
  LOADV(1, VSET1);
  {
    f32x16 ss = mfma32b(bc8(k0a), qf0, zz16);
    ss = mfma32b(bc8(k0b), qf1, ss);
    SM16(ss, P0, P1);
  }

  // steady state: t = 1..126 in odd/even pairs
  #pragma unroll 1
  for (int tt = 0; tt < 63; ++tt) {
    const int t = 2 * tt + 1;
    ITER(t,     KSET1, VSET0, KSET0, VSET0);   // odd t: QK K1, PV(t-1) V0, load t+1 -> K0,V0
    ITER(t + 1, KSET0, VSET1, KSET1, VSET1);   // even t: QK K0, PV V1, load -> K1,V1
  }

  // t = 127 (odd), no prefetch
  {
    f32x16 ss = mfma32b(bc8(k1a), qf0, zz16);
    ss = mfma32b(bc8(k1b), qf1, ss);
    PVONLY(VSET0);                             // PV(126), even -> V0
    SM16(ss, P0, P1);
  }
  PVONLY(VSET1);                               // PV(127) -> V1 (loaded at t=126)

  // denominator: lacc rows identical; cols repeat across g2 -> every lane holds
  // its q's full-range l. NO fold (MFMA already summed all 16 k-slots).
  const float ga = gamma0 / lacc[0];
  const int i = ibase + s * 32 + l31;

  STORE_CT(0, o0);
  STORE_CT(1, o1);
  STORE_CT(2, o2);
  STORE_CT(3, o3);
}

extern "C" void kernel_launch(void* const* d_in, const int* in_sizes, int n_in,
                              void* d_out, int out_size, void* d_ws, size_t ws_size,
                              hipStream_t stream) {
  const float* x     = (const float*)d_in[0];
  const float* Wq    = (const float*)d_in[1];
  const float* bq    = (const float*)d_in[2];
  const float* Wk    = (const float*)d_in[3];
  const float* bk    = (const float*)d_in[4];
  const float* Wv    = (const float*)d_in[5];
  const float* bv    = (const float*)d_in[6];
  const float* gamma = (const float*)d_in[7];
  float* out = (float*)d_out;

  unsigned short* QT = (unsigned short*)d_ws;
  unsigned short* KT = QT + (size_t)NB * NN * DQ;
  unsigned short* Vm = KT + (size_t)NB * NN * DQ;

  dim3 gridP(128, NB), blkP(256);
  proj_kernel<<<gridP, blkP, 0, stream>>>(x, Wq, bq, Wk, bk, Wv, bv, QT, KT, Vm);
  attn_kernel<<<256, 256, 0, stream>>>(QT, KT, Vm, x, gamma, out);
}